// Round 13
// baseline (427.213 us; speedup 1.0000x reference)
//
#include <hip/hip_runtime.h>

#define M_NODES 100000
#define N_EDGES_C 800000
#define IN_DIM_C 128
#define HID_C 256
#define N_GRAPHS_C 256
#define BN_EPS_C 1e-5f

typedef __attribute__((ext_vector_type(8))) short short8v;
typedef __attribute__((ext_vector_type(4))) float floatx4;

__device__ __forceinline__ unsigned short bf16_rne(float f) {
    union { float f; unsigned u; } x; x.f = f;
    unsigned r = x.u + 0x7FFF + ((x.u >> 16) & 1);
    return (unsigned short)(r >> 16);
}
__device__ __forceinline__ float bf16_to_f(unsigned short h) {
    union { unsigned u; float f; } x; x.u = ((unsigned)h) << 16;
    return x.f;
}
__device__ __forceinline__ float bf16lo_f(unsigned u) {
    union { unsigned u; float f; } x; x.u = u << 16;
    return x.f;
}
__device__ __forceinline__ float bf16hi_f(unsigned u) {
    union { unsigned u; float f; } x; x.u = u & 0xffff0000u;
    return x.f;
}

// fragment-major W offset
template <int K>
__device__ __forceinline__ long long woff(int c, int k) {
    return ((long long)((k >> 5) * 16 + (c >> 4))) * 512 + ((k >> 3) & 3) * 128 +
           (c & 15) * 8 + (k & 7);
}

template <int N8>
__device__ __forceinline__ void loadU(const unsigned short* p, unsigned* w) {
#pragma unroll
    for (int c = 0; c < N8; ++c) {
        uint4 u = *(const uint4*)(p + c * 8);
        w[c * 4 + 0] = u.x; w[c * 4 + 1] = u.y; w[c * 4 + 2] = u.z; w[c * 4 + 3] = u.w;
    }
}

// ---------------- small helpers ----------------
__global__ void zero_f(float* __restrict__ p, int n) {
    int i = blockIdx.x * blockDim.x + threadIdx.x;
    if (i < n) p[i] = 0.f;
}
__global__ void zero_i(int* __restrict__ p, int n) {
    int i = blockIdx.x * blockDim.x + threadIdx.x;
    if (i < n) p[i] = 0;
}
__global__ void copy_i(const int* __restrict__ s, int* __restrict__ d, int n) {
    int i = blockIdx.x * blockDim.x + threadIdx.x;
    if (i < n) d[i] = s[i];
}
__global__ void f2b(const float4* __restrict__ in, ushort4* __restrict__ out, int n4) {
    int i = blockIdx.x * blockDim.x + threadIdx.x;
    if (i >= n4) return;
    float4 v = in[i];
    ushort4 o;
    o.x = bf16_rne(v.x); o.y = bf16_rne(v.y); o.z = bf16_rne(v.z); o.w = bf16_rne(v.w);
    out[i] = o;
}

// ---------------- W -> fragment-major, single-plane (rounded bf16) ----------------
template <int K>
__global__ void wpack(const float* __restrict__ W, unsigned short* __restrict__ hi) {
    int t = blockIdx.x * blockDim.x + threadIdx.x;
    if (t >= K * HID_C) return;
    int k = t % K, c = t / K;
    hi[woff<K>(c, k)] = bf16_rne(W[(long long)k * HID_C + c]);
}

// ---------------- CSR build ----------------
__global__ void csr_count(const int* __restrict__ dst, int* __restrict__ counts) {
    int e = blockIdx.x * blockDim.x + threadIdx.x;
    if (e < N_EDGES_C) atomicAdd(&counts[dst[e]], 1);
}

__global__ __launch_bounds__(256) void block_scan(const int* __restrict__ counts,
                                                  int* __restrict__ excl,
                                                  int* __restrict__ partials) {
    __shared__ int sm[256];
    int i = blockIdx.x * 256 + threadIdx.x;
    int v = (i < M_NODES) ? counts[i] : 0;
    sm[threadIdx.x] = v;
    __syncthreads();
    for (int off = 1; off < 256; off <<= 1) {
        int add = (threadIdx.x >= off) ? sm[threadIdx.x - off] : 0;
        __syncthreads();
        sm[threadIdx.x] += add;
        __syncthreads();
    }
    if (i <= M_NODES) excl[i] = sm[threadIdx.x] - v;
    if (threadIdx.x == 255) partials[blockIdx.x] = sm[255];
}

__global__ __launch_bounds__(512) void scan_partials(int* __restrict__ partials, int nb) {
    __shared__ int sm[512];
    int t = threadIdx.x;
    int v = (t < nb) ? partials[t] : 0;
    sm[t] = v;
    __syncthreads();
    for (int off = 1; off < 512; off <<= 1) {
        int add = (t >= off) ? sm[t - off] : 0;
        __syncthreads();
        sm[t] += add;
        __syncthreads();
    }
    if (t < nb) partials[t] = sm[t] - v;
}

__global__ void add_offsets(int* __restrict__ rowptr, const int* __restrict__ partials) {
    int i = blockIdx.x * 256 + threadIdx.x;
    if (i <= M_NODES) rowptr[i] += partials[blockIdx.x];
}

__global__ void csr_fill(const int* __restrict__ src, const int* __restrict__ dst,
                         int* __restrict__ fillpos, int* __restrict__ csr_src) {
    int e = blockIdx.x * blockDim.x + threadIdx.x;
    if (e >= N_EDGES_C) return;
    int pos = atomicAdd(&fillpos[dst[e]], 1);
    csr_src[pos] = src[e];
}

// ---------------- fused GNN layer: gather -> MLP -> pre-BN bf16 out + BN col sums ----------------
// Phase G: gather 64 rows (optional BN+relu of prev layer) into swizzled LDS A-tile,
//          edge loop unrolled x4 with batched independent loads.
// Stage 1: H = relu(A@W1+b1), W1 single-plane -> overwrite LDS with H.
// Stage 2: out = H@W2+b2, W2 single-plane (BN after absorbs weight rounding).
template <int K, bool BN>
__global__ __launch_bounds__(256, 4) void fused_gnn(const unsigned short* __restrict__ Hin,
                                                    const int* __restrict__ rowptr,
                                                    const int* __restrict__ csr_src,
                                                    const float* __restrict__ ss,
                                                    const unsigned short* __restrict__ W1,
                                                    const float* __restrict__ b1,
                                                    const unsigned short* __restrict__ W2,
                                                    const float* __restrict__ b2,
                                                    unsigned short* __restrict__ outH,
                                                    int M, float* __restrict__ bnsums) {
    __shared__ char lds_raw[32768];  // A tile [64][K] then H tile [64][256], XOR-swizzled

    const int tid = threadIdx.x;
    const int lane = tid & 63;
    const int wc = tid >> 6;
    const int gm = blockIdx.x * 64;
    const int l15 = lane & 15;
    const int kgrp = lane >> 4;
    const int rgrp = kgrp * 4;
    const int laneoff = kgrp * 128 + l15 * 8;
    const int wquarter = wc * 4;

    // ---------- phase G: gather into LDS A ----------
    {
        constexpr int FPT = K / 16;   // feats per thread (8 or 16)
        const int fq = tid & 15;
        const int f0 = fq * FPT;
#pragma unroll
        for (int it = 0; it < 4; ++it) {
            int nl = it * 16 + (tid >> 4);
            int node = gm + nl;
            int nc = node < M ? node : M - 1;
            int beg = rowptr[nc], end = rowptr[nc + 1];
            float a[FPT], sc[FPT], sh[FPT];
            if (BN) {
#pragma unroll
                for (int i = 0; i < FPT; ++i) {
                    sc[i] = ss[f0 + i];
                    sh[i] = ss[HID_C + f0 + i];
                }
            }
            {
                unsigned w[FPT / 2];
                loadU<FPT / 8>(Hin + (long long)nc * K + f0, w);
#pragma unroll
                for (int i = 0; i < FPT / 2; ++i) {
                    float lo = bf16lo_f(w[i]), hi = bf16hi_f(w[i]);
                    a[2 * i] = BN ? fmaxf(fmaf(lo, sc[2 * i], sh[2 * i]), 0.f) : lo;
                    a[2 * i + 1] = BN ? fmaxf(fmaf(hi, sc[2 * i + 1], sh[2 * i + 1]), 0.f) : hi;
                }
            }
            // edge loop, unrolled x4: batch 4 independent row loads, then accumulate
            int e = beg;
            int e4 = beg + ((end - beg) & ~3);
            for (; e < e4; e += 4) {
                unsigned w4[4][FPT / 2];
#pragma unroll
                for (int u = 0; u < 4; ++u) {
                    long long s = csr_src[e + u];
                    loadU<FPT / 8>(Hin + s * K + f0, w4[u]);
                }
#pragma unroll
                for (int u = 0; u < 4; ++u)
#pragma unroll
                    for (int i = 0; i < FPT / 2; ++i) {
                        float lo = bf16lo_f(w4[u][i]), hi = bf16hi_f(w4[u][i]);
                        a[2 * i] += BN ? fmaxf(fmaf(lo, sc[2 * i], sh[2 * i]), 0.f) : lo;
                        a[2 * i + 1] += BN ? fmaxf(fmaf(hi, sc[2 * i + 1], sh[2 * i + 1]), 0.f) : hi;
                    }
            }
            for (; e < end; ++e) {
                long long s = csr_src[e];
                unsigned w[FPT / 2];
                loadU<FPT / 8>(Hin + s * K + f0, w);
#pragma unroll
                for (int i = 0; i < FPT / 2; ++i) {
                    float lo = bf16lo_f(w[i]), hi = bf16hi_f(w[i]);
                    a[2 * i] += BN ? fmaxf(fmaf(lo, sc[2 * i], sh[2 * i]), 0.f) : lo;
                    a[2 * i + 1] += BN ? fmaxf(fmaf(hi, sc[2 * i + 1], sh[2 * i + 1]), 0.f) : hi;
                }
            }
#pragma unroll
            for (int c = 0; c < FPT / 8; ++c) {
                uint4 v;
                v.x = (unsigned)bf16_rne(a[c * 8 + 0]) | ((unsigned)bf16_rne(a[c * 8 + 1]) << 16);
                v.y = (unsigned)bf16_rne(a[c * 8 + 2]) | ((unsigned)bf16_rne(a[c * 8 + 3]) << 16);
                v.z = (unsigned)bf16_rne(a[c * 8 + 4]) | ((unsigned)bf16_rne(a[c * 8 + 5]) << 16);
                v.w = (unsigned)bf16_rne(a[c * 8 + 6]) | ((unsigned)bf16_rne(a[c * 8 + 7]) << 16);
                int col = f0 + c * 8;
                int bo = (nl * (K * 2) + col * 2) ^ ((nl & 7) << 4);
                *(uint4*)(lds_raw + bo) = v;
            }
        }
    }
    __syncthreads();

    floatx4 acc[4][4];
#pragma unroll
    for (int i = 0; i < 4; ++i)
#pragma unroll
        for (int j = 0; j < 4; ++j) acc[i][j] = (floatx4){0.f, 0.f, 0.f, 0.f};

    // ---------- stage 1: H = relu(A@W1+b1), A from LDS, W1 single-plane ----------
#pragma unroll
    for (int k0 = 0; k0 < K; k0 += 32) {
        short8v af[4], bh[4];
#pragma unroll
        for (int i = 0; i < 4; ++i) {
            int row = i * 16 + l15;
            int bo = (row * (K * 2) + (k0 + kgrp * 8) * 2) ^ ((row & 7) << 4);
            af[i] = *(const short8v*)(lds_raw + bo);
        }
#pragma unroll
        for (int j = 0; j < 4; ++j) {
            long long wb = (long long)(k0 >> 5) * 8192 + (wquarter + j) * 512 + laneoff;
            bh[j] = *(const short8v*)(W1 + wb);
        }
#pragma unroll
        for (int i = 0; i < 4; ++i)
#pragma unroll
            for (int j = 0; j < 4; ++j)
                acc[i][j] = __builtin_amdgcn_mfma_f32_16x16x32_bf16(af[i], bh[j], acc[i][j], 0, 0, 0);
    }
    __syncthreads();  // A fully consumed; safe to overwrite with H

    // write relu'd bf16 H tile into swizzled LDS [64][256]
#pragma unroll
    for (int j = 0; j < 4; ++j) {
        int col = wc * 64 + j * 16 + l15;
        float bb = b1[col];
#pragma unroll
        for (int i = 0; i < 4; ++i) {
            int lrow = i * 16 + rgrp;
#pragma unroll
            for (int r = 0; r < 4; ++r) {
                int row = lrow + r;
                float v = fmaxf(acc[i][j][r] + bb, 0.f);
                int bo = (row * 512 + col * 2) ^ ((row & 7) << 4);
                *(unsigned short*)(lds_raw + bo) = bf16_rne(v);
            }
        }
    }
    __syncthreads();

    // ---------- stage 2: out = H@W2+b2, W2 single-plane ----------
#pragma unroll
    for (int i = 0; i < 4; ++i)
#pragma unroll
        for (int j = 0; j < 4; ++j) acc[i][j] = (floatx4){0.f, 0.f, 0.f, 0.f};

#pragma unroll
    for (int k0 = 0; k0 < HID_C; k0 += 32) {
        short8v af[4], bh[4];
#pragma unroll
        for (int i = 0; i < 4; ++i) {
            int row = i * 16 + l15;
            int bo = (row * 512 + (k0 + kgrp * 8) * 2) ^ ((row & 7) << 4);
            af[i] = *(const short8v*)(lds_raw + bo);
        }
#pragma unroll
        for (int j = 0; j < 4; ++j) {
            long long wb = (long long)(k0 >> 5) * 8192 + (wquarter + j) * 512 + laneoff;
            bh[j] = *(const short8v*)(W2 + wb);
        }
#pragma unroll
        for (int i = 0; i < 4; ++i)
#pragma unroll
            for (int j = 0; j < 4; ++j)
                acc[i][j] = __builtin_amdgcn_mfma_f32_16x16x32_bf16(af[i], bh[j], acc[i][j], 0, 0, 0);
    }

    // fused BN column sums (exact fp32 from accumulators)
#pragma unroll
    for (int j = 0; j < 4; ++j) {
        int col = wc * 64 + j * 16 + l15;
        float bb = b2[col];
        float s1 = 0.f, s2 = 0.f;
#pragma unroll
        for (int i = 0; i < 4; ++i) {
            int rowb = gm + i * 16 + rgrp;
#pragma unroll
            for (int r = 0; r < 4; ++r) {
                if (rowb + r < M) {
                    float v = acc[i][j][r] + bb;
                    s1 += v; s2 += v * v;
                }
            }
        }
        s1 += __shfl_xor(s1, 16); s1 += __shfl_xor(s1, 32);
        s2 += __shfl_xor(s2, 16); s2 += __shfl_xor(s2, 32);
        if ((lane >> 4) == 0) {
            atomicAdd(&bnsums[col], s1);
            atomicAdd(&bnsums[HID_C + col], s2);
        }
    }

    // coalesced bf16 epilogue via LDS (reuse lds_raw), 2 col-half phases
    unsigned short* stg = (unsigned short*)lds_raw;  // [64][132]
#pragma unroll
    for (int p = 0; p < 2; ++p) {
        __syncthreads();
        if ((wc >> 1) == p) {
#pragma unroll
            for (int j = 0; j < 4; ++j) {
                int col = wc * 64 + j * 16 + l15;
                int lcol = (wc & 1) * 64 + j * 16 + l15;
                float bb = b2[col];
#pragma unroll
                for (int i = 0; i < 4; ++i) {
                    int lrow = i * 16 + rgrp;
#pragma unroll
                    for (int r = 0; r < 4; ++r)
                        stg[(lrow + r) * 132 + lcol] = bf16_rne(acc[i][j][r] + bb);
                }
            }
        }
        __syncthreads();
#pragma unroll
        for (int it = 0; it < 8; ++it) {
            int idx = it * 256 + tid;
            int row = idx >> 5;
            int c4 = idx & 31;
            int grow = gm + row;
            if (grow < M)
                *(ushort4*)(outH + (long long)grow * HID_C + p * 128 + c4 * 4) =
                    *(const ushort4*)&stg[row * 132 + c4 * 4];
        }
    }
}

// ---------------- BatchNorm finalize ----------------
__global__ void bn_finalize(const float* __restrict__ sums, const float* __restrict__ gamma,
                            const float* __restrict__ beta, float* __restrict__ ss) {
    int f = threadIdx.x;
    float mean = sums[f] * (1.0f / M_NODES);
    float var = sums[HID_C + f] * (1.0f / M_NODES) - mean * mean;
    float sc = gamma[f] * rsqrtf(var + BN_EPS_C);
    ss[f] = sc;
    ss[HID_C + f] = beta[f] - mean * sc;
}

// ---------------- pooling (bf16 in, fused BN+relu) ----------------
#define POOL_BLOCKS 4096
#define POOL_RPB 25
__global__ void pool_bn(const unsigned short* __restrict__ h, const float* __restrict__ ss,
                        const int* __restrict__ batch, float* __restrict__ sums, int M) {
    int f = threadIdx.x;
    float sc = ss[f], sh = ss[HID_C + f];
    int r0 = blockIdx.x * POOL_RPB;
    if (r0 >= M) return;
    int r1 = r0 + POOL_RPB;
    if (r1 > M) r1 = M;
    int cur = batch[r0];
    float acc = 0.f;
    for (int r = r0; r < r1; ++r) {
        int g = batch[r];
        if (g != cur) {
            atomicAdd(&sums[(long long)cur * HID_C + f], acc);
            acc = 0.f;
            cur = g;
        }
        float v = bf16_to_f(h[(long long)r * HID_C + f]);
        acc += fmaxf(fmaf(v, sc, sh), 0.f);
    }
    atomicAdd(&sums[(long long)cur * HID_C + f], acc);
}

__device__ __forceinline__ int lower_bound_i(const int* a, int n, int v) {
    int lo = 0, hi = n;
    while (lo < hi) {
        int mid = (lo + hi) >> 1;
        if (a[mid] < v) lo = mid + 1;
        else hi = mid;
    }
    return lo;
}

__global__ void pool_finalize(const float* __restrict__ sums, const int* __restrict__ batch,
                              float* __restrict__ out) {
    int g = blockIdx.x, f = threadIdx.x;
    int lb = lower_bound_i(batch, M_NODES, g);
    int ub = lower_bound_i(batch, M_NODES, g + 1);
    float cnt = (float)(ub - lb);
    out[(long long)g * HID_C + f] = sums[(long long)g * HID_C + f] / fmaxf(cnt, 1.0f);
}

// ---------------- launch ----------------
extern "C" void kernel_launch(void* const* d_in, const int* in_sizes, int n_in,
                              void* d_out, int out_size, void* d_ws, size_t ws_size,
                              hipStream_t stream) {
    const float* x = (const float*)d_in[0];
    const int* ei = (const int*)d_in[1];
    const int* esrc = ei;
    const int* edst = ei + N_EDGES_C;
    const int* batch = (const int*)d_in[2];
    const float* W1_0 = (const float*)d_in[3];
    const float* b1_0 = (const float*)d_in[4];
    const float* W2_0 = (const float*)d_in[5];
    const float* b2_0 = (const float*)d_in[6];
    const float* g0 = (const float*)d_in[7];
    const float* be0 = (const float*)d_in[8];
    const float* W1_1 = (const float*)d_in[9];
    const float* b1_1 = (const float*)d_in[10];
    const float* W2_1 = (const float*)d_in[11];
    const float* b2_1 = (const float*)d_in[12];
    const float* g1 = (const float*)d_in[13];
    const float* be1 = (const float*)d_in[14];
    float* out = (float*)d_out;

    const long long NF = (long long)M_NODES * HID_C;
    const long long NI = (long long)M_NODES * IN_DIM_C;
    unsigned short* U = (unsigned short*)d_ws;
    unsigned short* X16 = U;           // NI  (bf16 x)
    unsigned short* Hb0 = U + NI;      // NF  (pre-BN out L0)
    unsigned short* Hb1 = Hb0 + NF;    // NF  (pre-BN out L1)
    float* fbase = (float*)(Hb1 + NF);
    float* bns = fbase;
    float* ss0 = bns + 2 * HID_C;
    float* ss1 = ss0 + 2 * HID_C;
    float* psum = ss1 + 2 * HID_C;
    int* counts = (int*)(psum + N_GRAPHS_C * HID_C);
    int* partials = counts + 100352;
    int* rowptr = partials + 512;
    int* csr_src = rowptr + 100004;
    unsigned short* wp = (unsigned short*)(csr_src + N_EDGES_C);
    unsigned short* w1A = wp;                      // 128*256 single-plane
    unsigned short* w2B = w1A + IN_DIM_C * HID_C;  // 256*256 single-plane
    unsigned short* w1C = w2B + HID_C * HID_C;
    unsigned short* w2D = w1C + HID_C * HID_C;

    dim3 blk(256);
    dim3 fgrid((M_NODES + 63) / 64);

    // ---- W packs (fragment-major, single-plane) ----
    wpack<IN_DIM_C><<<(IN_DIM_C * HID_C + 255) / 256, blk, 0, stream>>>(W1_0, w1A);
    wpack<HID_C><<<(HID_C * HID_C + 255) / 256, blk, 0, stream>>>(W2_0, w2B);
    wpack<HID_C><<<(HID_C * HID_C + 255) / 256, blk, 0, stream>>>(W1_1, w1C);
    wpack<HID_C><<<(HID_C * HID_C + 255) / 256, blk, 0, stream>>>(W2_1, w2D);

    // ---- CSR build ----
    zero_i<<<(M_NODES + 255) / 256, blk, 0, stream>>>(counts, M_NODES);
    csr_count<<<(N_EDGES_C + 255) / 256, blk, 0, stream>>>(edst, counts);
    block_scan<<<392, blk, 0, stream>>>(counts, rowptr, partials);
    scan_partials<<<1, 512, 0, stream>>>(partials, 392);
    add_offsets<<<392, blk, 0, stream>>>(rowptr, partials);
    copy_i<<<(M_NODES + 255) / 256, blk, 0, stream>>>(rowptr, counts, M_NODES);
    csr_fill<<<(N_EDGES_C + 255) / 256, blk, 0, stream>>>(esrc, edst, counts, csr_src);

    // ---- x -> bf16 ----
    f2b<<<(int)((NI / 4 + 255) / 256), blk, 0, stream>>>((const float4*)x, (ushort4*)X16,
                                                         (int)(NI / 4));

    // ---- Layer 0 (gather fused) ----
    zero_f<<<2, blk, 0, stream>>>(bns, 2 * HID_C);
    fused_gnn<IN_DIM_C, false><<<fgrid, blk, 0, stream>>>(X16, rowptr, csr_src, nullptr,
                                                          w1A, b1_0, w2B, b2_0,
                                                          Hb0, M_NODES, bns);
    bn_finalize<<<1, blk, 0, stream>>>(bns, g0, be0, ss0);

    // ---- Layer 1 (gather fused, prev-BN applied in gather) ----
    zero_f<<<2, blk, 0, stream>>>(bns, 2 * HID_C);
    fused_gnn<HID_C, true><<<fgrid, blk, 0, stream>>>(Hb0, rowptr, csr_src, ss0,
                                                      w1C, b1_1, w2D, b2_1,
                                                      Hb1, M_NODES, bns);
    bn_finalize<<<1, blk, 0, stream>>>(bns, g1, be1, ss1);

    // ---- Pool (fused BN+relu) ----
    zero_f<<<(N_GRAPHS_C * HID_C + 255) / 256, blk, 0, stream>>>(psum, N_GRAPHS_C * HID_C);
    pool_bn<<<POOL_BLOCKS, blk, 0, stream>>>(Hb1, ss1, batch, psum, M_NODES);
    pool_finalize<<<256, blk, 0, stream>>>(psum, batch, out);
}

// Round 14
// 417.348 us; speedup vs baseline: 1.0236x; 1.0236x over previous
//
#include <hip/hip_runtime.h>

#define M_NODES 100000
#define N_EDGES_C 800000
#define IN_DIM_C 128
#define HID_C 256
#define N_GRAPHS_C 256
#define BN_EPS_C 1e-5f

typedef __attribute__((ext_vector_type(8))) short short8v;
typedef __attribute__((ext_vector_type(4))) float floatx4;

__device__ __forceinline__ unsigned short bf16_rne(float f) {
    union { float f; unsigned u; } x; x.f = f;
    unsigned r = x.u + 0x7FFF + ((x.u >> 16) & 1);
    return (unsigned short)(r >> 16);
}
__device__ __forceinline__ float bf16_to_f(unsigned short h) {
    union { unsigned u; float f; } x; x.u = ((unsigned)h) << 16;
    return x.f;
}
__device__ __forceinline__ float bf16lo_f(unsigned u) {
    union { unsigned u; float f; } x; x.u = u << 16;
    return x.f;
}
__device__ __forceinline__ float bf16hi_f(unsigned u) {
    union { unsigned u; float f; } x; x.u = u & 0xffff0000u;
    return x.f;
}

// fragment-major W offset
template <int K>
__device__ __forceinline__ long long woff(int c, int k) {
    return ((long long)((k >> 5) * 16 + (c >> 4))) * 512 + ((k >> 3) & 3) * 128 +
           (c & 15) * 8 + (k & 7);
}

template <int N8>
__device__ __forceinline__ void loadU(const unsigned short* p, unsigned* w) {
#pragma unroll
    for (int c = 0; c < N8; ++c) {
        uint4 u = *(const uint4*)(p + c * 8);
        w[c * 4 + 0] = u.x; w[c * 4 + 1] = u.y; w[c * 4 + 2] = u.z; w[c * 4 + 3] = u.w;
    }
}

// ---------------- small helpers ----------------
__global__ void zero_f(float* __restrict__ p, int n) {
    int i = blockIdx.x * blockDim.x + threadIdx.x;
    if (i < n) p[i] = 0.f;
}
__global__ void zero_i(int* __restrict__ p, int n) {
    int i = blockIdx.x * blockDim.x + threadIdx.x;
    if (i < n) p[i] = 0;
}
__global__ void copy_i(const int* __restrict__ s, int* __restrict__ d, int n) {
    int i = blockIdx.x * blockDim.x + threadIdx.x;
    if (i < n) d[i] = s[i];
}
__global__ void f2b(const float4* __restrict__ in, ushort4* __restrict__ out, int n4) {
    int i = blockIdx.x * blockDim.x + threadIdx.x;
    if (i >= n4) return;
    float4 v = in[i];
    ushort4 o;
    o.x = bf16_rne(v.x); o.y = bf16_rne(v.y); o.z = bf16_rne(v.z); o.w = bf16_rne(v.w);
    out[i] = o;
}

// ---------------- W -> fragment-major, single-plane (rounded bf16) ----------------
template <int K>
__global__ void wpack(const float* __restrict__ W, unsigned short* __restrict__ hi) {
    int t = blockIdx.x * blockDim.x + threadIdx.x;
    if (t >= K * HID_C) return;
    int k = t % K, c = t / K;
    hi[woff<K>(c, k)] = bf16_rne(W[(long long)k * HID_C + c]);
}

// ---------------- CSR build ----------------
__global__ void csr_count(const int* __restrict__ dst, int* __restrict__ counts) {
    int e = blockIdx.x * blockDim.x + threadIdx.x;
    if (e < N_EDGES_C) atomicAdd(&counts[dst[e]], 1);
}

__global__ __launch_bounds__(256) void block_scan(const int* __restrict__ counts,
                                                  int* __restrict__ excl,
                                                  int* __restrict__ partials) {
    __shared__ int sm[256];
    int i = blockIdx.x * 256 + threadIdx.x;
    int v = (i < M_NODES) ? counts[i] : 0;
    sm[threadIdx.x] = v;
    __syncthreads();
    for (int off = 1; off < 256; off <<= 1) {
        int add = (threadIdx.x >= off) ? sm[threadIdx.x - off] : 0;
        __syncthreads();
        sm[threadIdx.x] += add;
        __syncthreads();
    }
    if (i <= M_NODES) excl[i] = sm[threadIdx.x] - v;
    if (threadIdx.x == 255) partials[blockIdx.x] = sm[255];
}

__global__ __launch_bounds__(512) void scan_partials(int* __restrict__ partials, int nb) {
    __shared__ int sm[512];
    int t = threadIdx.x;
    int v = (t < nb) ? partials[t] : 0;
    sm[t] = v;
    __syncthreads();
    for (int off = 1; off < 512; off <<= 1) {
        int add = (t >= off) ? sm[t - off] : 0;
        __syncthreads();
        sm[t] += add;
        __syncthreads();
    }
    if (t < nb) partials[t] = sm[t] - v;
}

__global__ void add_offsets(int* __restrict__ rowptr, const int* __restrict__ partials) {
    int i = blockIdx.x * 256 + threadIdx.x;
    if (i <= M_NODES) rowptr[i] += partials[blockIdx.x];
}

__global__ void csr_fill(const int* __restrict__ src, const int* __restrict__ dst,
                         int* __restrict__ fillpos, int* __restrict__ csr_src) {
    int e = blockIdx.x * blockDim.x + threadIdx.x;
    if (e >= N_EDGES_C) return;
    int pos = atomicAdd(&fillpos[dst[e]], 1);
    csr_src[pos] = src[e];
}

// ---------------- fused GNN layer: gather -> MLP -> pre-BN bf16 out + BN col sums ----------------
// Phase G: gather 64 rows (optional BN+relu of prev layer) into swizzled LDS A-tile.
// Stage 1: H = relu(A@W1+b1), W1 single-plane -> overwrite LDS with H.
// Stage 2: out = H@W2+b2, W2 single-plane (downstream BN absorbs weight rounding).
template <int K, bool BN>
__global__ __launch_bounds__(256, 4) void fused_gnn(const unsigned short* __restrict__ Hin,
                                                    const int* __restrict__ rowptr,
                                                    const int* __restrict__ csr_src,
                                                    const float* __restrict__ ss,
                                                    const unsigned short* __restrict__ W1,
                                                    const float* __restrict__ b1,
                                                    const unsigned short* __restrict__ W2,
                                                    const float* __restrict__ b2,
                                                    unsigned short* __restrict__ outH,
                                                    int M, float* __restrict__ bnsums) {
    __shared__ char lds_raw[32768];  // A tile [64][K] then H tile [64][256], XOR-swizzled

    const int tid = threadIdx.x;
    const int lane = tid & 63;
    const int wc = tid >> 6;
    const int gm = blockIdx.x * 64;
    const int l15 = lane & 15;
    const int kgrp = lane >> 4;
    const int rgrp = kgrp * 4;
    const int laneoff = kgrp * 128 + l15 * 8;
    const int wquarter = wc * 4;

    // ---------- phase G: gather into LDS A ----------
    {
        constexpr int FPT = K / 16;   // feats per thread (8 or 16)
        const int fq = tid & 15;
        const int f0 = fq * FPT;
#pragma unroll
        for (int it = 0; it < 4; ++it) {
            int nl = it * 16 + (tid >> 4);
            int node = gm + nl;
            int nc = node < M ? node : M - 1;
            int beg = rowptr[nc], end = rowptr[nc + 1];
            float a[FPT], sc[FPT], sh[FPT];
            if (BN) {
#pragma unroll
                for (int i = 0; i < FPT; ++i) {
                    sc[i] = ss[f0 + i];
                    sh[i] = ss[HID_C + f0 + i];
                }
            }
            {
                unsigned w[FPT / 2];
                loadU<FPT / 8>(Hin + (long long)nc * K + f0, w);
#pragma unroll
                for (int i = 0; i < FPT / 2; ++i) {
                    float lo = bf16lo_f(w[i]), hi = bf16hi_f(w[i]);
                    a[2 * i] = BN ? fmaxf(fmaf(lo, sc[2 * i], sh[2 * i]), 0.f) : lo;
                    a[2 * i + 1] = BN ? fmaxf(fmaf(hi, sc[2 * i + 1], sh[2 * i + 1]), 0.f) : hi;
                }
            }
            for (int e = beg; e < end; ++e) {
                long long s = csr_src[e];
                unsigned w[FPT / 2];
                loadU<FPT / 8>(Hin + s * K + f0, w);
#pragma unroll
                for (int i = 0; i < FPT / 2; ++i) {
                    float lo = bf16lo_f(w[i]), hi = bf16hi_f(w[i]);
                    a[2 * i] += BN ? fmaxf(fmaf(lo, sc[2 * i], sh[2 * i]), 0.f) : lo;
                    a[2 * i + 1] += BN ? fmaxf(fmaf(hi, sc[2 * i + 1], sh[2 * i + 1]), 0.f) : hi;
                }
            }
#pragma unroll
            for (int c = 0; c < FPT / 8; ++c) {
                uint4 v;
                v.x = (unsigned)bf16_rne(a[c * 8 + 0]) | ((unsigned)bf16_rne(a[c * 8 + 1]) << 16);
                v.y = (unsigned)bf16_rne(a[c * 8 + 2]) | ((unsigned)bf16_rne(a[c * 8 + 3]) << 16);
                v.z = (unsigned)bf16_rne(a[c * 8 + 4]) | ((unsigned)bf16_rne(a[c * 8 + 5]) << 16);
                v.w = (unsigned)bf16_rne(a[c * 8 + 6]) | ((unsigned)bf16_rne(a[c * 8 + 7]) << 16);
                int col = f0 + c * 8;
                int bo = (nl * (K * 2) + col * 2) ^ ((nl & 7) << 4);
                *(uint4*)(lds_raw + bo) = v;
            }
        }
    }
    __syncthreads();

    floatx4 acc[4][4];
#pragma unroll
    for (int i = 0; i < 4; ++i)
#pragma unroll
        for (int j = 0; j < 4; ++j) acc[i][j] = (floatx4){0.f, 0.f, 0.f, 0.f};

    // ---------- stage 1: H = relu(A@W1+b1), A from LDS, W1 single-plane ----------
#pragma unroll
    for (int k0 = 0; k0 < K; k0 += 32) {
        short8v af[4], bh[4];
#pragma unroll
        for (int i = 0; i < 4; ++i) {
            int row = i * 16 + l15;
            int bo = (row * (K * 2) + (k0 + kgrp * 8) * 2) ^ ((row & 7) << 4);
            af[i] = *(const short8v*)(lds_raw + bo);
        }
#pragma unroll
        for (int j = 0; j < 4; ++j) {
            long long wb = (long long)(k0 >> 5) * 8192 + (wquarter + j) * 512 + laneoff;
            bh[j] = *(const short8v*)(W1 + wb);
        }
#pragma unroll
        for (int i = 0; i < 4; ++i)
#pragma unroll
            for (int j = 0; j < 4; ++j)
                acc[i][j] = __builtin_amdgcn_mfma_f32_16x16x32_bf16(af[i], bh[j], acc[i][j], 0, 0, 0);
    }
    __syncthreads();  // A fully consumed; safe to overwrite with H

    // write relu'd bf16 H tile into swizzled LDS [64][256]
#pragma unroll
    for (int j = 0; j < 4; ++j) {
        int col = wc * 64 + j * 16 + l15;
        float bb = b1[col];
#pragma unroll
        for (int i = 0; i < 4; ++i) {
            int lrow = i * 16 + rgrp;
#pragma unroll
            for (int r = 0; r < 4; ++r) {
                int row = lrow + r;
                float v = fmaxf(acc[i][j][r] + bb, 0.f);
                int bo = (row * 512 + col * 2) ^ ((row & 7) << 4);
                *(unsigned short*)(lds_raw + bo) = bf16_rne(v);
            }
        }
    }
    __syncthreads();

    // ---------- stage 2: out = H@W2+b2, W2 single-plane ----------
#pragma unroll
    for (int i = 0; i < 4; ++i)
#pragma unroll
        for (int j = 0; j < 4; ++j) acc[i][j] = (floatx4){0.f, 0.f, 0.f, 0.f};

#pragma unroll
    for (int k0 = 0; k0 < HID_C; k0 += 32) {
        short8v af[4], bh[4];
#pragma unroll
        for (int i = 0; i < 4; ++i) {
            int row = i * 16 + l15;
            int bo = (row * 512 + (k0 + kgrp * 8) * 2) ^ ((row & 7) << 4);
            af[i] = *(const short8v*)(lds_raw + bo);
        }
#pragma unroll
        for (int j = 0; j < 4; ++j) {
            long long wb = (long long)(k0 >> 5) * 8192 + (wquarter + j) * 512 + laneoff;
            bh[j] = *(const short8v*)(W2 + wb);
        }
#pragma unroll
        for (int i = 0; i < 4; ++i)
#pragma unroll
            for (int j = 0; j < 4; ++j)
                acc[i][j] = __builtin_amdgcn_mfma_f32_16x16x32_bf16(af[i], bh[j], acc[i][j], 0, 0, 0);
    }

    // fused BN column sums (exact fp32 from accumulators)
#pragma unroll
    for (int j = 0; j < 4; ++j) {
        int col = wc * 64 + j * 16 + l15;
        float bb = b2[col];
        float s1 = 0.f, s2 = 0.f;
#pragma unroll
        for (int i = 0; i < 4; ++i) {
            int rowb = gm + i * 16 + rgrp;
#pragma unroll
            for (int r = 0; r < 4; ++r) {
                if (rowb + r < M) {
                    float v = acc[i][j][r] + bb;
                    s1 += v; s2 += v * v;
                }
            }
        }
        s1 += __shfl_xor(s1, 16); s1 += __shfl_xor(s1, 32);
        s2 += __shfl_xor(s2, 16); s2 += __shfl_xor(s2, 32);
        if ((lane >> 4) == 0) {
            atomicAdd(&bnsums[col], s1);
            atomicAdd(&bnsums[HID_C + col], s2);
        }
    }

    // coalesced bf16 epilogue via LDS (reuse lds_raw), 2 col-half phases
    unsigned short* stg = (unsigned short*)lds_raw;  // [64][132]
#pragma unroll
    for (int p = 0; p < 2; ++p) {
        __syncthreads();
        if ((wc >> 1) == p) {
#pragma unroll
            for (int j = 0; j < 4; ++j) {
                int col = wc * 64 + j * 16 + l15;
                int lcol = (wc & 1) * 64 + j * 16 + l15;
                float bb = b2[col];
#pragma unroll
                for (int i = 0; i < 4; ++i) {
                    int lrow = i * 16 + rgrp;
#pragma unroll
                    for (int r = 0; r < 4; ++r)
                        stg[(lrow + r) * 132 + lcol] = bf16_rne(acc[i][j][r] + bb);
                }
            }
        }
        __syncthreads();
#pragma unroll
        for (int it = 0; it < 8; ++it) {
            int idx = it * 256 + tid;
            int row = idx >> 5;
            int c4 = idx & 31;
            int grow = gm + row;
            if (grow < M)
                *(ushort4*)(outH + (long long)grow * HID_C + p * 128 + c4 * 4) =
                    *(const ushort4*)&stg[row * 132 + c4 * 4];
        }
    }
}

// ---------------- BatchNorm finalize ----------------
__global__ void bn_finalize(const float* __restrict__ sums, const float* __restrict__ gamma,
                            const float* __restrict__ beta, float* __restrict__ ss) {
    int f = threadIdx.x;
    float mean = sums[f] * (1.0f / M_NODES);
    float var = sums[HID_C + f] * (1.0f / M_NODES) - mean * mean;
    float sc = gamma[f] * rsqrtf(var + BN_EPS_C);
    ss[f] = sc;
    ss[HID_C + f] = beta[f] - mean * sc;
}

// ---------------- pooling (bf16 in, fused BN+relu) ----------------
#define POOL_BLOCKS 4096
#define POOL_RPB 25
__global__ void pool_bn(const unsigned short* __restrict__ h, const float* __restrict__ ss,
                        const int* __restrict__ batch, float* __restrict__ sums, int M) {
    int f = threadIdx.x;
    float sc = ss[f], sh = ss[HID_C + f];
    int r0 = blockIdx.x * POOL_RPB;
    if (r0 >= M) return;
    int r1 = r0 + POOL_RPB;
    if (r1 > M) r1 = M;
    int cur = batch[r0];
    float acc = 0.f;
    for (int r = r0; r < r1; ++r) {
        int g = batch[r];
        if (g != cur) {
            atomicAdd(&sums[(long long)cur * HID_C + f], acc);
            acc = 0.f;
            cur = g;
        }
        float v = bf16_to_f(h[(long long)r * HID_C + f]);
        acc += fmaxf(fmaf(v, sc, sh), 0.f);
    }
    atomicAdd(&sums[(long long)cur * HID_C + f], acc);
}

__device__ __forceinline__ int lower_bound_i(const int* a, int n, int v) {
    int lo = 0, hi = n;
    while (lo < hi) {
        int mid = (lo + hi) >> 1;
        if (a[mid] < v) lo = mid + 1;
        else hi = mid;
    }
    return lo;
}

__global__ void pool_finalize(const float* __restrict__ sums, const int* __restrict__ batch,
                              float* __restrict__ out) {
    int g = blockIdx.x, f = threadIdx.x;
    int lb = lower_bound_i(batch, M_NODES, g);
    int ub = lower_bound_i(batch, M_NODES, g + 1);
    float cnt = (float)(ub - lb);
    out[(long long)g * HID_C + f] = sums[(long long)g * HID_C + f] / fmaxf(cnt, 1.0f);
}

// ---------------- launch ----------------
extern "C" void kernel_launch(void* const* d_in, const int* in_sizes, int n_in,
                              void* d_out, int out_size, void* d_ws, size_t ws_size,
                              hipStream_t stream) {
    const float* x = (const float*)d_in[0];
    const int* ei = (const int*)d_in[1];
    const int* esrc = ei;
    const int* edst = ei + N_EDGES_C;
    const int* batch = (const int*)d_in[2];
    const float* W1_0 = (const float*)d_in[3];
    const float* b1_0 = (const float*)d_in[4];
    const float* W2_0 = (const float*)d_in[5];
    const float* b2_0 = (const float*)d_in[6];
    const float* g0 = (const float*)d_in[7];
    const float* be0 = (const float*)d_in[8];
    const float* W1_1 = (const float*)d_in[9];
    const float* b1_1 = (const float*)d_in[10];
    const float* W2_1 = (const float*)d_in[11];
    const float* b2_1 = (const float*)d_in[12];
    const float* g1 = (const float*)d_in[13];
    const float* be1 = (const float*)d_in[14];
    float* out = (float*)d_out;

    const long long NF = (long long)M_NODES * HID_C;
    const long long NI = (long long)M_NODES * IN_DIM_C;
    unsigned short* U = (unsigned short*)d_ws;
    unsigned short* X16 = U;           // NI  (bf16 x)
    unsigned short* Hb0 = U + NI;      // NF  (pre-BN out L0)
    unsigned short* Hb1 = Hb0 + NF;    // NF  (pre-BN out L1)
    float* fbase = (float*)(Hb1 + NF);
    float* bns = fbase;
    float* ss0 = bns + 2 * HID_C;
    float* ss1 = ss0 + 2 * HID_C;
    float* psum = ss1 + 2 * HID_C;
    int* counts = (int*)(psum + N_GRAPHS_C * HID_C);
    int* partials = counts + 100352;
    int* rowptr = partials + 512;
    int* csr_src = rowptr + 100004;
    unsigned short* wp = (unsigned short*)(csr_src + N_EDGES_C);
    unsigned short* w1A = wp;                      // 128*256 single-plane
    unsigned short* w2B = w1A + IN_DIM_C * HID_C;  // 256*256 single-plane
    unsigned short* w1C = w2B + HID_C * HID_C;
    unsigned short* w2D = w1C + HID_C * HID_C;

    dim3 blk(256);
    dim3 fgrid((M_NODES + 63) / 64);

    // ---- W packs (fragment-major, single-plane) ----
    wpack<IN_DIM_C><<<(IN_DIM_C * HID_C + 255) / 256, blk, 0, stream>>>(W1_0, w1A);
    wpack<HID_C><<<(HID_C * HID_C + 255) / 256, blk, 0, stream>>>(W2_0, w2B);
    wpack<HID_C><<<(HID_C * HID_C + 255) / 256, blk, 0, stream>>>(W1_1, w1C);
    wpack<HID_C><<<(HID_C * HID_C + 255) / 256, blk, 0, stream>>>(W2_1, w2D);

    // ---- CSR build ----
    zero_i<<<(M_NODES + 255) / 256, blk, 0, stream>>>(counts, M_NODES);
    csr_count<<<(N_EDGES_C + 255) / 256, blk, 0, stream>>>(edst, counts);
    block_scan<<<392, blk, 0, stream>>>(counts, rowptr, partials);
    scan_partials<<<1, 512, 0, stream>>>(partials, 392);
    add_offsets<<<392, blk, 0, stream>>>(rowptr, partials);
    copy_i<<<(M_NODES + 255) / 256, blk, 0, stream>>>(rowptr, counts, M_NODES);
    csr_fill<<<(N_EDGES_C + 255) / 256, blk, 0, stream>>>(esrc, edst, counts, csr_src);

    // ---- x -> bf16 ----
    f2b<<<(int)((NI / 4 + 255) / 256), blk, 0, stream>>>((const float4*)x, (ushort4*)X16,
                                                         (int)(NI / 4));

    // ---- Layer 0 (gather fused) ----
    zero_f<<<2, blk, 0, stream>>>(bns, 2 * HID_C);
    fused_gnn<IN_DIM_C, false><<<fgrid, blk, 0, stream>>>(X16, rowptr, csr_src, nullptr,
                                                          w1A, b1_0, w2B, b2_0,
                                                          Hb0, M_NODES, bns);
    bn_finalize<<<1, blk, 0, stream>>>(bns, g0, be0, ss0);

    // ---- Layer 1 (gather fused, prev-BN applied in gather) ----
    zero_f<<<2, blk, 0, stream>>>(bns, 2 * HID_C);
    fused_gnn<HID_C, true><<<fgrid, blk, 0, stream>>>(Hb0, rowptr, csr_src, ss0,
                                                      w1C, b1_1, w2D, b2_1,
                                                      Hb1, M_NODES, bns);
    bn_finalize<<<1, blk, 0, stream>>>(bns, g1, be1, ss1);

    // ---- Pool (fused BN+relu) ----
    zero_f<<<(N_GRAPHS_C * HID_C + 255) / 256, blk, 0, stream>>>(psum, N_GRAPHS_C * HID_C);
    pool_bn<<<POOL_BLOCKS, blk, 0, stream>>>(Hb1, ss1, batch, psum, M_NODES);
    pool_finalize<<<256, blk, 0, stream>>>(psum, batch, out);
}

// Round 15
// 403.794 us; speedup vs baseline: 1.0580x; 1.0336x over previous
//
#include <hip/hip_runtime.h>

#define M_NODES 100000
#define N_EDGES_C 800000
#define IN_DIM_C 128
#define HID_C 256
#define N_GRAPHS_C 256
#define BN_EPS_C 1e-5f

typedef __attribute__((ext_vector_type(8))) short short8v;
typedef __attribute__((ext_vector_type(4))) float floatx4;

__device__ __forceinline__ unsigned short bf16_rne(float f) {
    union { float f; unsigned u; } x; x.f = f;
    unsigned r = x.u + 0x7FFF + ((x.u >> 16) & 1);
    return (unsigned short)(r >> 16);
}
__device__ __forceinline__ float bf16_to_f(unsigned short h) {
    union { unsigned u; float f; } x; x.u = ((unsigned)h) << 16;
    return x.f;
}
__device__ __forceinline__ float bf16lo_f(unsigned u) {
    union { unsigned u; float f; } x; x.u = u << 16;
    return x.f;
}
__device__ __forceinline__ float bf16hi_f(unsigned u) {
    union { unsigned u; float f; } x; x.u = u & 0xffff0000u;
    return x.f;
}

// fragment-major W offset
template <int K>
__device__ __forceinline__ long long woff(int c, int k) {
    return ((long long)((k >> 5) * 16 + (c >> 4))) * 512 + ((k >> 3) & 3) * 128 +
           (c & 15) * 8 + (k & 7);
}

template <int N8>
__device__ __forceinline__ void loadU(const unsigned short* p, unsigned* w) {
#pragma unroll
    for (int c = 0; c < N8; ++c) {
        uint4 u = *(const uint4*)(p + c * 8);
        w[c * 4 + 0] = u.x; w[c * 4 + 1] = u.y; w[c * 4 + 2] = u.z; w[c * 4 + 3] = u.w;
    }
}

// ---------------- small helpers ----------------
__global__ void zero_f(float* __restrict__ p, int n) {
    int i = blockIdx.x * blockDim.x + threadIdx.x;
    if (i < n) p[i] = 0.f;
}
__global__ void zero_i(int* __restrict__ p, int n) {
    int i = blockIdx.x * blockDim.x + threadIdx.x;
    if (i < n) p[i] = 0;
}
__global__ void copy_i(const int* __restrict__ s, int* __restrict__ d, int n) {
    int i = blockIdx.x * blockDim.x + threadIdx.x;
    if (i < n) d[i] = s[i];
}
__global__ void f2b(const float4* __restrict__ in, ushort4* __restrict__ out, int n4) {
    int i = blockIdx.x * blockDim.x + threadIdx.x;
    if (i >= n4) return;
    float4 v = in[i];
    ushort4 o;
    o.x = bf16_rne(v.x); o.y = bf16_rne(v.y); o.z = bf16_rne(v.z); o.w = bf16_rne(v.w);
    out[i] = o;
}

// ---------------- W -> fragment-major, single-plane (rounded bf16) ----------------
template <int K>
__global__ void wpack(const float* __restrict__ W, unsigned short* __restrict__ hi) {
    int t = blockIdx.x * blockDim.x + threadIdx.x;
    if (t >= K * HID_C) return;
    int k = t % K, c = t / K;
    hi[woff<K>(c, k)] = bf16_rne(W[(long long)k * HID_C + c]);
}

// ---------------- CSR build ----------------
__global__ void csr_count(const int* __restrict__ dst, int* __restrict__ counts) {
    int e = blockIdx.x * blockDim.x + threadIdx.x;
    if (e < N_EDGES_C) atomicAdd(&counts[dst[e]], 1);
}

__global__ __launch_bounds__(256) void block_scan(const int* __restrict__ counts,
                                                  int* __restrict__ excl,
                                                  int* __restrict__ partials) {
    __shared__ int sm[256];
    int i = blockIdx.x * 256 + threadIdx.x;
    int v = (i < M_NODES) ? counts[i] : 0;
    sm[threadIdx.x] = v;
    __syncthreads();
    for (int off = 1; off < 256; off <<= 1) {
        int add = (threadIdx.x >= off) ? sm[threadIdx.x - off] : 0;
        __syncthreads();
        sm[threadIdx.x] += add;
        __syncthreads();
    }
    if (i <= M_NODES) excl[i] = sm[threadIdx.x] - v;
    if (threadIdx.x == 255) partials[blockIdx.x] = sm[255];
}

__global__ __launch_bounds__(512) void scan_partials(int* __restrict__ partials, int nb) {
    __shared__ int sm[512];
    int t = threadIdx.x;
    int v = (t < nb) ? partials[t] : 0;
    sm[t] = v;
    __syncthreads();
    for (int off = 1; off < 512; off <<= 1) {
        int add = (t >= off) ? sm[t - off] : 0;
        __syncthreads();
        sm[t] += add;
        __syncthreads();
    }
    if (t < nb) partials[t] = sm[t] - v;
}

__global__ void add_offsets(int* __restrict__ rowptr, const int* __restrict__ partials) {
    int i = blockIdx.x * 256 + threadIdx.x;
    if (i <= M_NODES) rowptr[i] += partials[blockIdx.x];
}

__global__ void csr_fill(const int* __restrict__ src, const int* __restrict__ dst,
                         int* __restrict__ fillpos, int* __restrict__ csr_src) {
    int e = blockIdx.x * blockDim.x + threadIdx.x;
    if (e >= N_EDGES_C) return;
    int pos = atomicAdd(&fillpos[dst[e]], 1);
    csr_src[pos] = src[e];
}

// ---------------- fused GNN layer, 512 threads / 8 waves ----------------
// Phase G: gather 64 rows into swizzled LDS A-tile (32 node-threads x 16 feat-threads).
// Stage 1: H = relu(A@W1+b1), W1 single-plane; each wave owns a 32-col slice.
// Stage 2: out = H@W2+b2, W2 single-plane. BN col sums fused.
template <int K, bool BN>
__global__ __launch_bounds__(512, 6) void fused_gnn(const unsigned short* __restrict__ Hin,
                                                    const int* __restrict__ rowptr,
                                                    const int* __restrict__ csr_src,
                                                    const float* __restrict__ ss,
                                                    const unsigned short* __restrict__ W1,
                                                    const float* __restrict__ b1,
                                                    const unsigned short* __restrict__ W2,
                                                    const float* __restrict__ b2,
                                                    unsigned short* __restrict__ outH,
                                                    int M, float* __restrict__ bnsums) {
    __shared__ char lds_raw[32768];  // A tile [64][K] then H tile [64][256], XOR-swizzled

    const int tid = threadIdx.x;
    const int lane = tid & 63;
    const int wv = tid >> 6;          // 0..7, owns cols [wv*32, wv*32+32)
    const int gm = blockIdx.x * 64;
    const int l15 = lane & 15;
    const int kgrp = lane >> 4;
    const int rgrp = kgrp * 4;
    const int laneoff = kgrp * 128 + l15 * 8;

    // ---------- phase G: gather into LDS A ----------
    {
        constexpr int FPT = K / 16;   // feats per thread (8 or 16)
        const int fq = tid & 15;
        const int f0 = fq * FPT;
#pragma unroll
        for (int it = 0; it < 2; ++it) {
            int nl = it * 32 + (tid >> 4);
            int node = gm + nl;
            int nc = node < M ? node : M - 1;
            int beg = rowptr[nc], end = rowptr[nc + 1];
            float a[FPT], sc[FPT], sh[FPT];
            if (BN) {
#pragma unroll
                for (int i = 0; i < FPT; ++i) {
                    sc[i] = ss[f0 + i];
                    sh[i] = ss[HID_C + f0 + i];
                }
            }
            {
                unsigned w[FPT / 2];
                loadU<FPT / 8>(Hin + (long long)nc * K + f0, w);
#pragma unroll
                for (int i = 0; i < FPT / 2; ++i) {
                    float lo = bf16lo_f(w[i]), hi = bf16hi_f(w[i]);
                    a[2 * i] = BN ? fmaxf(fmaf(lo, sc[2 * i], sh[2 * i]), 0.f) : lo;
                    a[2 * i + 1] = BN ? fmaxf(fmaf(hi, sc[2 * i + 1], sh[2 * i + 1]), 0.f) : hi;
                }
            }
            for (int e = beg; e < end; ++e) {
                long long s = csr_src[e];
                unsigned w[FPT / 2];
                loadU<FPT / 8>(Hin + s * K + f0, w);
#pragma unroll
                for (int i = 0; i < FPT / 2; ++i) {
                    float lo = bf16lo_f(w[i]), hi = bf16hi_f(w[i]);
                    a[2 * i] += BN ? fmaxf(fmaf(lo, sc[2 * i], sh[2 * i]), 0.f) : lo;
                    a[2 * i + 1] += BN ? fmaxf(fmaf(hi, sc[2 * i + 1], sh[2 * i + 1]), 0.f) : hi;
                }
            }
#pragma unroll
            for (int c = 0; c < FPT / 8; ++c) {
                uint4 v;
                v.x = (unsigned)bf16_rne(a[c * 8 + 0]) | ((unsigned)bf16_rne(a[c * 8 + 1]) << 16);
                v.y = (unsigned)bf16_rne(a[c * 8 + 2]) | ((unsigned)bf16_rne(a[c * 8 + 3]) << 16);
                v.z = (unsigned)bf16_rne(a[c * 8 + 4]) | ((unsigned)bf16_rne(a[c * 8 + 5]) << 16);
                v.w = (unsigned)bf16_rne(a[c * 8 + 6]) | ((unsigned)bf16_rne(a[c * 8 + 7]) << 16);
                int col = f0 + c * 8;
                int bo = (nl * (K * 2) + col * 2) ^ ((nl & 7) << 4);
                *(uint4*)(lds_raw + bo) = v;
            }
        }
    }
    __syncthreads();

    floatx4 acc[4][2];
#pragma unroll
    for (int i = 0; i < 4; ++i)
#pragma unroll
        for (int j = 0; j < 2; ++j) acc[i][j] = (floatx4){0.f, 0.f, 0.f, 0.f};

    // ---------- stage 1: H = relu(A@W1+b1), A from LDS, W1 single-plane ----------
#pragma unroll
    for (int k0 = 0; k0 < K; k0 += 32) {
        short8v af[4], bh[2];
#pragma unroll
        for (int i = 0; i < 4; ++i) {
            int row = i * 16 + l15;
            int bo = (row * (K * 2) + (k0 + kgrp * 8) * 2) ^ ((row & 7) << 4);
            af[i] = *(const short8v*)(lds_raw + bo);
        }
#pragma unroll
        for (int j = 0; j < 2; ++j) {
            long long wb = (long long)((k0 >> 5) * 16 + wv * 2 + j) * 512 + laneoff;
            bh[j] = *(const short8v*)(W1 + wb);
        }
#pragma unroll
        for (int i = 0; i < 4; ++i)
#pragma unroll
            for (int j = 0; j < 2; ++j)
                acc[i][j] = __builtin_amdgcn_mfma_f32_16x16x32_bf16(af[i], bh[j], acc[i][j], 0, 0, 0);
    }
    __syncthreads();  // A fully consumed; safe to overwrite with H

    // write relu'd bf16 H tile into swizzled LDS [64][256]
#pragma unroll
    for (int j = 0; j < 2; ++j) {
        int col = wv * 32 + j * 16 + l15;
        float bb = b1[col];
#pragma unroll
        for (int i = 0; i < 4; ++i) {
            int lrow = i * 16 + rgrp;
#pragma unroll
            for (int r = 0; r < 4; ++r) {
                int row = lrow + r;
                float v = fmaxf(acc[i][j][r] + bb, 0.f);
                int bo = (row * 512 + col * 2) ^ ((row & 7) << 4);
                *(unsigned short*)(lds_raw + bo) = bf16_rne(v);
            }
        }
    }
    __syncthreads();

    // ---------- stage 2: out = H@W2+b2, W2 single-plane ----------
#pragma unroll
    for (int i = 0; i < 4; ++i)
#pragma unroll
        for (int j = 0; j < 2; ++j) acc[i][j] = (floatx4){0.f, 0.f, 0.f, 0.f};

#pragma unroll
    for (int k0 = 0; k0 < HID_C; k0 += 32) {
        short8v af[4], bh[2];
#pragma unroll
        for (int i = 0; i < 4; ++i) {
            int row = i * 16 + l15;
            int bo = (row * 512 + (k0 + kgrp * 8) * 2) ^ ((row & 7) << 4);
            af[i] = *(const short8v*)(lds_raw + bo);
        }
#pragma unroll
        for (int j = 0; j < 2; ++j) {
            long long wb = (long long)((k0 >> 5) * 16 + wv * 2 + j) * 512 + laneoff;
            bh[j] = *(const short8v*)(W2 + wb);
        }
#pragma unroll
        for (int i = 0; i < 4; ++i)
#pragma unroll
            for (int j = 0; j < 2; ++j)
                acc[i][j] = __builtin_amdgcn_mfma_f32_16x16x32_bf16(af[i], bh[j], acc[i][j], 0, 0, 0);
    }

    // fused BN column sums (exact fp32 from accumulators)
#pragma unroll
    for (int j = 0; j < 2; ++j) {
        int col = wv * 32 + j * 16 + l15;
        float bb = b2[col];
        float s1 = 0.f, s2 = 0.f;
#pragma unroll
        for (int i = 0; i < 4; ++i) {
            int rowb = gm + i * 16 + rgrp;
#pragma unroll
            for (int r = 0; r < 4; ++r) {
                if (rowb + r < M) {
                    float v = acc[i][j][r] + bb;
                    s1 += v; s2 += v * v;
                }
            }
        }
        s1 += __shfl_xor(s1, 16); s1 += __shfl_xor(s1, 32);
        s2 += __shfl_xor(s2, 16); s2 += __shfl_xor(s2, 32);
        if ((lane >> 4) == 0) {
            atomicAdd(&bnsums[col], s1);
            atomicAdd(&bnsums[HID_C + col], s2);
        }
    }

    // coalesced bf16 epilogue via LDS (reuse lds_raw), 2 col-half phases
    unsigned short* stg = (unsigned short*)lds_raw;  // [64][132]
#pragma unroll
    for (int p = 0; p < 2; ++p) {
        __syncthreads();
        if ((wv >> 2) == p) {
#pragma unroll
            for (int j = 0; j < 2; ++j) {
                int col = wv * 32 + j * 16 + l15;
                int lcol = (wv & 3) * 32 + j * 16 + l15;
                float bb = b2[col];
#pragma unroll
                for (int i = 0; i < 4; ++i) {
                    int lrow = i * 16 + rgrp;
#pragma unroll
                    for (int r = 0; r < 4; ++r)
                        stg[(lrow + r) * 132 + lcol] = bf16_rne(acc[i][j][r] + bb);
                }
            }
        }
        __syncthreads();
#pragma unroll
        for (int it = 0; it < 4; ++it) {
            int idx = it * 512 + tid;
            int row = idx >> 5;
            int c4 = idx & 31;
            int grow = gm + row;
            if (grow < M)
                *(ushort4*)(outH + (long long)grow * HID_C + p * 128 + c4 * 4) =
                    *(const ushort4*)&stg[row * 132 + c4 * 4];
        }
    }
}

// ---------------- BatchNorm finalize ----------------
__global__ void bn_finalize(const float* __restrict__ sums, const float* __restrict__ gamma,
                            const float* __restrict__ beta, float* __restrict__ ss) {
    int f = threadIdx.x;
    float mean = sums[f] * (1.0f / M_NODES);
    float var = sums[HID_C + f] * (1.0f / M_NODES) - mean * mean;
    float sc = gamma[f] * rsqrtf(var + BN_EPS_C);
    ss[f] = sc;
    ss[HID_C + f] = beta[f] - mean * sc;
}

// ---------------- pooling (bf16 in, fused BN+relu) ----------------
#define POOL_BLOCKS 4096
#define POOL_RPB 25
__global__ void pool_bn(const unsigned short* __restrict__ h, const float* __restrict__ ss,
                        const int* __restrict__ batch, float* __restrict__ sums, int M) {
    int f = threadIdx.x;
    float sc = ss[f], sh = ss[HID_C + f];
    int r0 = blockIdx.x * POOL_RPB;
    if (r0 >= M) return;
    int r1 = r0 + POOL_RPB;
    if (r1 > M) r1 = M;
    int cur = batch[r0];
    float acc = 0.f;
    for (int r = r0; r < r1; ++r) {
        int g = batch[r];
        if (g != cur) {
            atomicAdd(&sums[(long long)cur * HID_C + f], acc);
            acc = 0.f;
            cur = g;
        }
        float v = bf16_to_f(h[(long long)r * HID_C + f]);
        acc += fmaxf(fmaf(v, sc, sh), 0.f);
    }
    atomicAdd(&sums[(long long)cur * HID_C + f], acc);
}

__device__ __forceinline__ int lower_bound_i(const int* a, int n, int v) {
    int lo = 0, hi = n;
    while (lo < hi) {
        int mid = (lo + hi) >> 1;
        if (a[mid] < v) lo = mid + 1;
        else hi = mid;
    }
    return lo;
}

__global__ void pool_finalize(const float* __restrict__ sums, const int* __restrict__ batch,
                              float* __restrict__ out) {
    int g = blockIdx.x, f = threadIdx.x;
    int lb = lower_bound_i(batch, M_NODES, g);
    int ub = lower_bound_i(batch, M_NODES, g + 1);
    float cnt = (float)(ub - lb);
    out[(long long)g * HID_C + f] = sums[(long long)g * HID_C + f] / fmaxf(cnt, 1.0f);
}

// ---------------- launch ----------------
extern "C" void kernel_launch(void* const* d_in, const int* in_sizes, int n_in,
                              void* d_out, int out_size, void* d_ws, size_t ws_size,
                              hipStream_t stream) {
    const float* x = (const float*)d_in[0];
    const int* ei = (const int*)d_in[1];
    const int* esrc = ei;
    const int* edst = ei + N_EDGES_C;
    const int* batch = (const int*)d_in[2];
    const float* W1_0 = (const float*)d_in[3];
    const float* b1_0 = (const float*)d_in[4];
    const float* W2_0 = (const float*)d_in[5];
    const float* b2_0 = (const float*)d_in[6];
    const float* g0 = (const float*)d_in[7];
    const float* be0 = (const float*)d_in[8];
    const float* W1_1 = (const float*)d_in[9];
    const float* b1_1 = (const float*)d_in[10];
    const float* W2_1 = (const float*)d_in[11];
    const float* b2_1 = (const float*)d_in[12];
    const float* g1 = (const float*)d_in[13];
    const float* be1 = (const float*)d_in[14];
    float* out = (float*)d_out;

    const long long NF = (long long)M_NODES * HID_C;
    const long long NI = (long long)M_NODES * IN_DIM_C;
    unsigned short* U = (unsigned short*)d_ws;
    unsigned short* X16 = U;           // NI  (bf16 x)
    unsigned short* Hb0 = U + NI;      // NF  (pre-BN out L0)
    unsigned short* Hb1 = Hb0 + NF;    // NF  (pre-BN out L1)
    float* fbase = (float*)(Hb1 + NF);
    float* bns = fbase;
    float* ss0 = bns + 2 * HID_C;
    float* ss1 = ss0 + 2 * HID_C;
    float* psum = ss1 + 2 * HID_C;
    int* counts = (int*)(psum + N_GRAPHS_C * HID_C);
    int* partials = counts + 100352;
    int* rowptr = partials + 512;
    int* csr_src = rowptr + 100004;
    unsigned short* wp = (unsigned short*)(csr_src + N_EDGES_C);
    unsigned short* w1A = wp;                      // 128*256 single-plane
    unsigned short* w2B = w1A + IN_DIM_C * HID_C;  // 256*256 single-plane
    unsigned short* w1C = w2B + HID_C * HID_C;
    unsigned short* w2D = w1C + HID_C * HID_C;

    dim3 blk(256);
    dim3 fgrid((M_NODES + 63) / 64);

    // ---- W packs (fragment-major, single-plane) ----
    wpack<IN_DIM_C><<<(IN_DIM_C * HID_C + 255) / 256, blk, 0, stream>>>(W1_0, w1A);
    wpack<HID_C><<<(HID_C * HID_C + 255) / 256, blk, 0, stream>>>(W2_0, w2B);
    wpack<HID_C><<<(HID_C * HID_C + 255) / 256, blk, 0, stream>>>(W1_1, w1C);
    wpack<HID_C><<<(HID_C * HID_C + 255) / 256, blk, 0, stream>>>(W2_1, w2D);

    // ---- CSR build ----
    zero_i<<<(M_NODES + 255) / 256, blk, 0, stream>>>(counts, M_NODES);
    csr_count<<<(N_EDGES_C + 255) / 256, blk, 0, stream>>>(edst, counts);
    block_scan<<<392, blk, 0, stream>>>(counts, rowptr, partials);
    scan_partials<<<1, 512, 0, stream>>>(partials, 392);
    add_offsets<<<392, blk, 0, stream>>>(rowptr, partials);
    copy_i<<<(M_NODES + 255) / 256, blk, 0, stream>>>(rowptr, counts, M_NODES);
    csr_fill<<<(N_EDGES_C + 255) / 256, blk, 0, stream>>>(esrc, edst, counts, csr_src);

    // ---- x -> bf16 ----
    f2b<<<(int)((NI / 4 + 255) / 256), blk, 0, stream>>>((const float4*)x, (ushort4*)X16,
                                                         (int)(NI / 4));

    // ---- Layer 0 (gather fused) ----
    zero_f<<<2, blk, 0, stream>>>(bns, 2 * HID_C);
    fused_gnn<IN_DIM_C, false><<<fgrid, dim3(512), 0, stream>>>(X16, rowptr, csr_src, nullptr,
                                                                w1A, b1_0, w2B, b2_0,
                                                                Hb0, M_NODES, bns);
    bn_finalize<<<1, blk, 0, stream>>>(bns, g0, be0, ss0);

    // ---- Layer 1 (gather fused, prev-BN applied in gather) ----
    zero_f<<<2, blk, 0, stream>>>(bns, 2 * HID_C);
    fused_gnn<HID_C, true><<<fgrid, dim3(512), 0, stream>>>(Hb0, rowptr, csr_src, ss0,
                                                            w1C, b1_1, w2D, b2_1,
                                                            Hb1, M_NODES, bns);
    bn_finalize<<<1, blk, 0, stream>>>(bns, g1, be1, ss1);

    // ---- Pool (fused BN+relu) ----
    zero_f<<<(N_GRAPHS_C * HID_C + 255) / 256, blk, 0, stream>>>(psum, N_GRAPHS_C * HID_C);
    pool_bn<<<POOL_BLOCKS, blk, 0, stream>>>(Hb1, ss1, batch, psum, M_NODES);
    pool_finalize<<<256, blk, 0, stream>>>(psum, batch, out);
}